// Round 8
// baseline (164.578 us; speedup 1.0000x reference)
//
#include <hip/hip_runtime.h>
#include <hip/hip_bf16.h>

#define KDIM 4096
#define NTILE 64                 // K-tiles of 64
#define NELEM16 (1u << 24)       // 4096*4096 elems per matrix

typedef float f32x4 __attribute__((ext_vector_type(4)));
typedef short bf16x8 __attribute__((ext_vector_type(8)));

typedef const __attribute__((address_space(1))) unsigned int g_u32;
typedef __attribute__((address_space(3))) unsigned int l_u32;

__device__ __forceinline__ void gload_lds16(const void* g, void* l) {
    __builtin_amdgcn_global_load_lds((g_u32*)g, (l_u32*)l, 16, 0, 0);
}

__device__ __forceinline__ unsigned int pack_bf16x2(float lo, float hi) {
    __hip_bfloat162 h = __float22bfloat162_rn(float2{lo, hi});
    union { __hip_bfloat162 h; unsigned int u; } c; c.h = h; return c.u;
}

// ---- pack pass ----
// x -> A-image: [rt16][kt64][half2][rl128][cp8][8e], content col-chunk = (cp^(rl&7))*8  (XOR-swz)
// W -> B-frag image: [ot16][kt64][cf16][s2][lane64][8e], content:
//      W[ot*256+cf*16+(lane&15)][kt*64+s*32+(lane>>4)*8 + e]   (fragment-contiguous, coalesced)
__global__ __launch_bounds__(256)
void pack2(const float* __restrict__ x, const float* __restrict__ W,
           unsigned short* __restrict__ xb, unsigned short* __restrict__ wb)
{
    const unsigned int stride = gridDim.x * blockDim.x;
    for (unsigned int i = blockIdx.x * blockDim.x + threadIdx.x; i < (1u << 22); i += stride) {
        const float* __restrict__ in;
        unsigned short* __restrict__ out;
        unsigned int row, col, E;
        if (i < (1u << 21)) {                    // A-image (x)
            const unsigned int cp = i & 7;
            const unsigned int rl = (i >> 3) & 127;
            const unsigned int c  = cp ^ (rl & 7);
            const unsigned int h  = (i >> 10) & 1;
            const unsigned int kt = (i >> 11) & 63;
            const unsigned int rt = i >> 17;
            row = rt * 256 + h * 128 + rl;
            col = kt * 64 + c * 8;
            in = x; out = xb; E = i * 8;
        } else {                                 // B-frag image (W)
            const unsigned int j    = i - (1u << 21);
            const unsigned int lane = j & 63;
            const unsigned int s    = (j >> 6) & 1;
            const unsigned int cf   = (j >> 7) & 15;
            const unsigned int kt   = (j >> 11) & 63;
            const unsigned int ot   = j >> 17;
            row = ot * 256 + cf * 16 + (lane & 15);
            col = kt * 64 + s * 32 + (lane >> 4) * 8;
            in = W; out = wb; E = j * 8;
        }
        const float4* sp = (const float4*)(in + (size_t)row * KDIM + col);
        const float4 a = sp[0], b = sp[1];
        uint4 o;
        o.x = pack_bf16x2(a.x, a.y); o.y = pack_bf16x2(a.z, a.w);
        o.z = pack_bf16x2(b.x, b.y); o.w = pack_bf16x2(b.z, b.w);
        *(uint4*)(out + (size_t)E) = o;
    }
}

// ---- 256x256 GEMM: A via LDS (swizzled, gload_lds), B global-direct to regs ----
// LDS (A only, 64 KiB): buf*16384 + half*8192 + rowfrag*1024 + c15*64 + swzchunk*8
#define STAGE_A(kt, h, bufn)                                                    \
    {                                                                           \
        const unsigned short* g_ = Abase + ((size_t)(kt) * 2 + (h)) * 8192;     \
        const unsigned int lo_ = (bufn) * 16384 + (h) * 8192 + wid * 1024;      \
        gload_lds16(g_ + stageOff,       &lds[lo_]);                            \
        gload_lds16(g_ + stageOff + 512, &lds[lo_ + 512]);                      \
    }

#define READ_A(dst, base)                                                       \
    _Pragma("unroll") for (int m = 0; m < 4; ++m)                               \
      _Pragma("unroll") for (int k = 0; k < 2; ++k)                             \
        dst[m][k] = *(const bf16x8*)&lds[(base) + (m * 2 + wm) * 1024 + rdBase + kcp[k]];

// B fragments for global n-frags {nbase, nbase+1}: coalesced dwordx4 per frag
#define LOAD_B(dst, t, nbase)                                                   \
    _Pragma("unroll") for (int n = 0; n < 2; ++n)                               \
      _Pragma("unroll") for (int s = 0; s < 2; ++s)                             \
        dst[n][s] = *(const bf16x8*)&Bbase[(size_t)(t) * 16384 +                \
            ((((nbase) + n) * 4 + wn) * 2 + s) * 512 + lane * 8];

#define MFMA32(AF, BF0, BF1, MO)                                                \
    __builtin_amdgcn_s_setprio(1);                                              \
    _Pragma("unroll") for (int m = 0; m < 4; ++m)                               \
      _Pragma("unroll") for (int n = 0; n < 2; ++n)                             \
        _Pragma("unroll") for (int k = 0; k < 2; ++k)                           \
          acc[(MO) + m][n] = __builtin_amdgcn_mfma_f32_16x16x32_bf16(           \
              AF[m][k], BF0[n][k], acc[(MO) + m][n], 0, 0, 0);                  \
    _Pragma("unroll") for (int m = 0; m < 4; ++m)                               \
      _Pragma("unroll") for (int n = 0; n < 2; ++n)                             \
        _Pragma("unroll") for (int k = 0; k < 2; ++k)                           \
          acc[(MO) + m][2 + n] = __builtin_amdgcn_mfma_f32_16x16x32_bf16(       \
              AF[m][k], BF1[n][k], acc[(MO) + m][2 + n], 0, 0, 0);              \
    __builtin_amdgcn_s_setprio(0);

// Per tile T: two half-tiles, ONE barrier each, 32 uninterrupted MFMAs each.
//   H1: [readA0; issue {stageA0(T+1), loadB0n(T+1)}; vmcnt(6); BAR; MFMA(A0,b0c),(A0,b1c)]
//   H2: [readA1; issue {stageA1(T+1), loadB1n(T+1)}; vmcnt(6); BAR; MFMA(A1,b1c),(A1,b0c)]
// vmcnt(6): 6 VMEM ops per half-tile; waiting to 6 drains exactly the previous
// half's group -> A-stage RAW satisfied one half before its ds_read; B-regs ready
// one half before first use. WAR on LDS: staged region's readers completed >= 1
// full barrier earlier. B current/next are separate named banks (even/odd tile).
#define TILE_BODY(t, PB, BUFN, C0, C1, N0, N1)                                  \
    {                                                                           \
        READ_A(afr, (PB));                                                      \
        if ((t) + 1 < NTILE) {                                                  \
            STAGE_A((t) + 1, 0, BUFN);                                          \
            LOAD_B(N0, (t) + 1, 0);                                             \
            asm volatile("s_waitcnt vmcnt(6)" ::: "memory");                    \
        } else {                                                                \
            asm volatile("s_waitcnt vmcnt(0)" ::: "memory");                    \
        }                                                                       \
        __builtin_amdgcn_s_barrier();                                           \
        __builtin_amdgcn_sched_barrier(0);                                      \
        MFMA32(afr, C0, C1, 0);                                                 \
        READ_A(afr, (PB) + 8192);                                               \
        if ((t) + 1 < NTILE) {                                                  \
            STAGE_A((t) + 1, 1, BUFN);                                          \
            LOAD_B(N1, (t) + 1, 2);                                             \
            asm volatile("s_waitcnt vmcnt(6)" ::: "memory");                    \
        } else {                                                                \
            asm volatile("s_waitcnt vmcnt(0)" ::: "memory");                    \
        }                                                                       \
        __builtin_amdgcn_s_barrier();                                           \
        __builtin_amdgcn_sched_barrier(0);                                      \
        MFMA32R(afr, C1, C0, 4);                                                \
    }

// second half-tile: clusters ordered (A1,b1) then (A1,b0)
#define MFMA32R(AF, BF1, BF0, MO)                                               \
    __builtin_amdgcn_s_setprio(1);                                              \
    _Pragma("unroll") for (int m = 0; m < 4; ++m)                               \
      _Pragma("unroll") for (int n = 0; n < 2; ++n)                             \
        _Pragma("unroll") for (int k = 0; k < 2; ++k)                           \
          acc[(MO) + m][2 + n] = __builtin_amdgcn_mfma_f32_16x16x32_bf16(       \
              AF[m][k], BF1[n][k], acc[(MO) + m][2 + n], 0, 0, 0);              \
    _Pragma("unroll") for (int m = 0; m < 4; ++m)                               \
      _Pragma("unroll") for (int n = 0; n < 2; ++n)                             \
        _Pragma("unroll") for (int k = 0; k < 2; ++k)                           \
          acc[(MO) + m][n] = __builtin_amdgcn_mfma_f32_16x16x32_bf16(           \
              AF[m][k], BF0[n][k], acc[(MO) + m][n], 0, 0, 0);                  \
    __builtin_amdgcn_s_setprio(0);

__global__ __launch_bounds__(512, 1)
void gemm_bdirect(const unsigned short* __restrict__ A,
                  const unsigned short* __restrict__ B,
                  const float* __restrict__ bias,
                  float* __restrict__ out)
{
    __shared__ unsigned short lds[32768];   // 64 KiB, A only: [buf2][half2][8192]

    const int tid  = threadIdx.x;
    const int lane = tid & 63;
    const int wid  = tid >> 6;     // 0..7
    const int wm   = wid >> 2;     // 0..1
    const int wn   = wid & 3;      // 0..3
    const int c15  = lane & 15;
    const int q4   = lane >> 4;
    const int c7   = c15 & 7;

    // 256 blocks = 16x16 output tiles; XCD-bijective swizzle (256 % 8 == 0)
    const int bid = blockIdx.x;
    const int wg  = (bid & 7) * 32 + (bid >> 3);
    const int bm  = wg >> 4;
    const int bn  = wg & 15;

    const unsigned short* Abase = A + (size_t)bm * 64 * 2 * 8192;
    const unsigned short* Bbase = B + ((size_t)bn << 20);

    const int stageOff = wid * 1024 + lane * 8;   // elem offset within a 16KB half
    const int rdBase   = c15 * 64;
    const int kcp[2]   = { ((0 + q4) ^ c7) * 8, ((4 + q4) ^ c7) * 8 };

    f32x4 acc[8][4];
    #pragma unroll
    for (int i = 0; i < 8; ++i)
        #pragma unroll
        for (int j = 0; j < 4; ++j)
            acc[i][j] = (f32x4)0.0f;

    bf16x8 afr[4][2];                    // A fragments (A0 in H1, A1 in H2)
    bf16x8 bE0[2][2], bE1[2][2];         // B banks, even tiles
    bf16x8 bO0[2][2], bO1[2][2];         // B banks, odd tiles

    // prologue: stage A(tile0) -> buf0; load B(tile0) -> even bank
    STAGE_A(0, 0, 0);
    STAGE_A(0, 1, 0);
    LOAD_B(bE0, 0, 0);
    LOAD_B(bE1, 0, 2);
    asm volatile("s_waitcnt vmcnt(8)" ::: "memory");   // A stages landed; B in flight (reg-tracked)
    __builtin_amdgcn_s_barrier();
    __builtin_amdgcn_sched_barrier(0);

    for (int tt = 0; tt < NTILE; tt += 2) {
        TILE_BODY(tt,     0,     1, bE0, bE1, bO0, bO1);
        TILE_BODY(tt + 1, 16384, 0, bO0, bO1, bE0, bE1);
    }

    // Epilogue: bias + maxpool(4 along col) + sum + atomic row add.
    // C/D frag: col = c15, row = q4*4 + r. Wave cols: (nf*4+wn)*16 + c15.
    float rs[8][4];
    #pragma unroll
    for (int mf = 0; mf < 8; ++mf)
        #pragma unroll
        for (int r = 0; r < 4; ++r)
            rs[mf][r] = 0.0f;

    #pragma unroll
    for (int nf = 0; nf < 4; ++nf) {
        const float bv = bias[bn * 256 + (nf * 4 + wn) * 16 + c15];
        #pragma unroll
        for (int mf = 0; mf < 8; ++mf) {
            #pragma unroll
            for (int r = 0; r < 4; ++r) {
                float v = acc[mf][nf][r] + bv;
                v = fmaxf(v, __shfl_xor(v, 1));
                v = fmaxf(v, __shfl_xor(v, 2));
                v += __shfl_xor(v, 4);
                v += __shfl_xor(v, 8);
                rs[mf][r] += v;
            }
        }
    }

    if (c15 == 0) {
        #pragma unroll
        for (int mf = 0; mf < 8; ++mf)
            #pragma unroll
            for (int r = 0; r < 4; ++r) {
                const int row = bm * 256 + (mf * 2 + wm) * 16 + q4 * 4 + r;
                atomicAdd(&out[row], 0.5f * rs[mf][r]);
            }
    }
}

// ---------------- fallback (round-1 kernel, verified) if d_ws too small ----------------
__global__ __launch_bounds__(256, 2)
void fused_gemm_pool_fallback(const float* __restrict__ x,
                              const float* __restrict__ W,
                              const float* __restrict__ b,
                              float* __restrict__ out)
{
    __shared__ unsigned short As[128][72];
    __shared__ unsigned short Bs[128][72];

    const int tid  = threadIdx.x;
    const int lane = tid & 63;
    const int wid  = tid >> 6;
    const int wm   = wid >> 1;
    const int wn   = wid & 1;

    const int bid = blockIdx.x;
    const int wg  = (bid & 7) * 128 + (bid >> 3);
    const int bm  = wg >> 5;
    const int bn  = wg & 31;

    const int srow = tid >> 4;
    const int scol = tid & 15;

    const float* xbase = x + (size_t)(bm * 128 + srow) * KDIM + scol * 4;
    const float* wbase = W + (size_t)(bn * 128 + srow) * KDIM + scol * 4;

    f32x4 acc[4][4];
    #pragma unroll
    for (int i = 0; i < 4; ++i)
        #pragma unroll
        for (int j = 0; j < 4; ++j)
            acc[i][j] = (f32x4)0.0f;

    float4 ra[8], rb[8];
    #pragma unroll
    for (int p = 0; p < 8; ++p) {
        ra[p] = *(const float4*)(xbase + (size_t)(p * 16) * KDIM);
        rb[p] = *(const float4*)(wbase + (size_t)(p * 16) * KDIM);
    }

    for (int kt = 0; kt < KDIM / 64; ++kt) {
        #pragma unroll
        for (int p = 0; p < 8; ++p) {
            const int r = srow + p * 16;
            uint2 pa, pb;
            pa.x = pack_bf16x2(ra[p].x, ra[p].y);
            pa.y = pack_bf16x2(ra[p].z, ra[p].w);
            pb.x = pack_bf16x2(rb[p].x, rb[p].y);
            pb.y = pack_bf16x2(rb[p].z, rb[p].w);
            *(uint2*)&As[r][scol * 4] = pa;
            *(uint2*)&Bs[r][scol * 4] = pb;
        }
        __syncthreads();

        if (kt + 1 < KDIM / 64) {
            const float* xa = xbase + (size_t)(kt + 1) * 64;
            const float* wa = wbase + (size_t)(kt + 1) * 64;
            #pragma unroll
            for (int p = 0; p < 8; ++p) {
                ra[p] = *(const float4*)(xa + (size_t)(p * 16) * KDIM);
                rb[p] = *(const float4*)(wa + (size_t)(p * 16) * KDIM);
            }
        }

        #pragma unroll
        for (int k0 = 0; k0 < 2; ++k0) {
            const int kk = k0 * 32 + (lane >> 4) * 8;
            bf16x8 af[4], bfr[4];
            #pragma unroll
            for (int mf = 0; mf < 4; ++mf)
                af[mf] = *(const bf16x8*)&As[wm * 64 + mf * 16 + (lane & 15)][kk];
            #pragma unroll
            for (int nf = 0; nf < 4; ++nf)
                bfr[nf] = *(const bf16x8*)&Bs[wn * 64 + nf * 16 + (lane & 15)][kk];
            #pragma unroll
            for (int mf = 0; mf < 4; ++mf)
                #pragma unroll
                for (int nf = 0; nf < 4; ++nf)
                    acc[mf][nf] = __builtin_amdgcn_mfma_f32_16x16x32_bf16(
                        af[mf], bfr[nf], acc[mf][nf], 0, 0, 0);
        }
        __syncthreads();
    }

    float rs[4][4];
    #pragma unroll
    for (int mf = 0; mf < 4; ++mf)
        #pragma unroll
        for (int r = 0; r < 4; ++r)
            rs[mf][r] = 0.0f;

    #pragma unroll
    for (int nf = 0; nf < 4; ++nf) {
        const float bv = b[bn * 128 + wn * 64 + nf * 16 + (lane & 15)];
        #pragma unroll
        for (int mf = 0; mf < 4; ++mf) {
            #pragma unroll
            for (int r = 0; r < 4; ++r) {
                float v = acc[mf][nf][r] + bv;
                v = fmaxf(v, __shfl_xor(v, 1));
                v = fmaxf(v, __shfl_xor(v, 2));
                v += __shfl_xor(v, 4);
                v += __shfl_xor(v, 8);
                rs[mf][r] += v;
            }
        }
    }

    if ((lane & 15) == 0) {
        #pragma unroll
        for (int mf = 0; mf < 4; ++mf)
            #pragma unroll
            for (int r = 0; r < 4; ++r) {
                const int row = bm * 128 + wm * 64 + mf * 16 + (lane >> 4) * 4 + r;
                atomicAdd(&out[row], 0.5f * rs[mf][r]);
            }
    }
}

extern "C" void kernel_launch(void* const* d_in, const int* in_sizes, int n_in,
                              void* d_out, int out_size, void* d_ws, size_t ws_size,
                              hipStream_t stream) {
    const float* x = (const float*)d_in[0];
    const float* W = (const float*)d_in[1];
    const float* b = (const float*)d_in[2];
    float* out = (float*)d_out;

    hipMemsetAsync(out, 0, (size_t)out_size * sizeof(float), stream);

    const size_t need = (size_t)NELEM16 * 2 * sizeof(unsigned short); // 64 MB
    if (ws_size >= need) {
        unsigned short* xb = (unsigned short*)d_ws;
        unsigned short* wb = xb + (size_t)NELEM16;
        pack2<<<dim3(2048), dim3(256), 0, stream>>>(x, W, xb, wb);
        gemm_bdirect<<<dim3(256), dim3(512), 0, stream>>>(xb, wb, b, out);
    } else {
        fused_gemm_pool_fallback<<<dim3(1024), dim3(256), 0, stream>>>(x, W, b, out);
    }
}